// Round 7
// baseline (117.325 us; speedup 1.0000x reference)
//
#include <hip/hip_runtime.h>
#include <math.h>

#define HH 512
#define WW 512
#define NA 180
#define ND 729
#define NB 2

// ws layout (float units):
//   [0]                completion counter (memset to 0 each launch)
//   [1024, 1024+360)   interleaved {cos,sin} per angle
//   [2048 + b*192)     P0[b][0..180]   (exclusive prefix of f[b][a][0])
//   [2560 + b*192)     P728[b][0..180] (exclusive prefix of f[b][a][728])
//   [4096, ...)        filtered sinograms
#define WS_CS 1024
#define WS_P0 2048
#define WS_P728 2560
#define WS_FILT 4096

// Ram-Lak spatial kernel (closed form, infinite-sum identity; tail < 1e-7/tap,
// empirically validated R2-R6): g[d] = (0.125 + min(d,729-d)/1458)/729.
// g is PIECEWISE LINEAR in d => the 729-tap circular convolution reduces to
// O(1) per output using prefix moments of the row:
//   P[k] = sum_{j<k} x[j],  Q[k] = sum_{j<k} j*x[j]  (double precision)
//   filtered[n] = c0*X + c1*( A(n) + B(n) ),  c0 = 0.125/729, c1 = 1/(1458*729)
//   A(n) = sum_{d=1}^{364} d*x[(n-d) mod 729]
//        = n>=364 ? n*(P[n]-P[n-364]) - (Q[n]-Q[n-364])
//                 : n*P[n] - Q[n] + (n+729)*(X-P[n+365]) - (M-Q[n+365])
//   B(n) = sum_{d=1}^{364} d*x[(n+d) mod 729]
//        = n<=364 ? (Q[n+365]-Q[n+1]) - n*(P[n+365]-P[n+1])
//                 : (M-Q[n+1]) - n*(X-P[n+1]) + Q[n-364] + (729-n)*P[n-364]
// One block per row; block 360 writes the angle tables; the last data block
// to finish computes the P0/P728 angle-prefix sums (last-block-done, counter
// memset to 0 on stream; pattern HW-validated in R5).
__global__ __launch_bounds__(256, 1) void k_fused(const float* __restrict__ sino,
                                                  float* __restrict__ ws) {
    int blk = blockIdx.x;
    int tid = threadIdx.x;
    if (blk == 360) {   // angle tables
        for (int t = tid; t < NA; t += 256) {
            double ang = M_PI * (double)t / (double)(NA - 1);
            ws[WS_CS + 2 * t] = (float)cos(ang);
            ws[WS_CS + 2 * t + 1] = (float)sin(ang);
        }
        return;
    }
    __shared__ float xs[736];
    __shared__ double Pd[730], Qd[730];
    __shared__ double sp[256], sq[256];
    __shared__ float fbuf[256];
    __shared__ int last;
    const float* x = sino + blk * ND;
    for (int i = tid; i < 736; i += 256) xs[i] = (i < ND) ? x[i] : 0.0f;
    __syncthreads();
    // per-thread partials over j in [3t, 3t+3)
    double lx = 0.0, lq = 0.0;
    if (tid < 243) {
        #pragma unroll
        for (int k = 0; k < 3; ++k) {
            int j = 3 * tid + k;
            double v = (double)xs[j];
            lx += v;
            lq += (double)j * v;
        }
    }
    sp[tid] = lx;
    sq[tid] = lq;
    __syncthreads();
    // inclusive Hillis-Steele scan of the 256 partials
    for (int off = 1; off < 256; off <<= 1) {
        double ap = (tid >= off) ? sp[tid - off] : 0.0;
        double aq = (tid >= off) ? sq[tid - off] : 0.0;
        __syncthreads();
        sp[tid] += ap;
        sq[tid] += aq;
        __syncthreads();
    }
    // exclusive prefixes P[0..729], Q[0..729]
    if (tid < 243) {
        double bp_ = tid ? sp[tid - 1] : 0.0;
        double bq_ = tid ? sq[tid - 1] : 0.0;
        #pragma unroll
        for (int k = 0; k < 3; ++k) {
            int j = 3 * tid + k;
            Pd[j] = bp_;
            Qd[j] = bq_;
            double v = (double)xs[j];
            bp_ += v;
            bq_ += (double)j * v;
        }
    }
    if (tid == 0) { Pd[ND] = sp[242]; Qd[ND] = sq[242]; }
    __syncthreads();
    const double X = Pd[ND], M = Qd[ND];
    const double c0 = 0.125 / 729.0;
    const double c1 = 1.0 / (1458.0 * 729.0);
    float* f = ws + WS_FILT + blk * ND;
    for (int n = tid; n < ND; n += 256) {
        double dn = (double)n;
        double A, Bv;
        if (n >= 364) A = dn * (Pd[n] - Pd[n - 364]) - (Qd[n] - Qd[n - 364]);
        else          A = dn * Pd[n] - Qd[n]
                        + (dn + 729.0) * (X - Pd[n + 365]) - (M - Qd[n + 365]);
        if (n <= 364) Bv = (Qd[n + 365] - Qd[n + 1]) - dn * (Pd[n + 365] - Pd[n + 1]);
        else          Bv = (M - Qd[n + 1]) - dn * (X - Pd[n + 1])
                         + Qd[n - 364] + (729.0 - dn) * Pd[n - 364];
        f[n] = (float)(c0 * X + c1 * (A + Bv));
    }
    // last-block-done: 360th data block computes the P0/P728 prefix sums
    __threadfence();
    __syncthreads();
    if (tid == 0) last = atomicAdd((int*)ws, 1);
    __syncthreads();
    if (last != 359) return;
    __threadfence();
    for (int q = 0; q < 4; ++q) {
        int b = q >> 1;
        int col = (q & 1) ? (ND - 1) : 0;
        float v = 0.f;
        if (tid < NA) v = ws[WS_FILT + (b * NA + tid) * ND + col];
        fbuf[tid] = v;
        __syncthreads();
        for (int off = 1; off < 256; off <<= 1) {
            float add = (tid >= off) ? fbuf[tid - off] : 0.f;
            __syncthreads();
            fbuf[tid] += add;
            __syncthreads();
        }
        int base = ((q & 1) ? WS_P728 : WS_P0) + b * 192;
        if (tid == 0) ws[base] = 0.f;
        if (tid < NA) ws[base + tid + 1] = fbuf[tid];
        __syncthreads();
    }
}

// Backprojection. idx(a) = clip(trunc((rot*c1)*729), 0, 728), rot = xc*cos+yc*sin.
// For r>=16 the angle axis splits into [low | band | high | band | low]:
//   high (idx=728): rot >= 6.27457  <=>  |a-phi| <= theta, theta = acos(6.27457/r)
//   low  (idx=0):   rot <  0.008619 <=>  |a-phi| >  ~pi/2
// Edges via atan2f/acosf (+-1 index guard, ~250x float-error margin); guarded
// band uses exact original arithmetic; clamped cores use prefix sums.
__global__ __launch_bounds__(256) void k_bp(const float* __restrict__ ws,
                                            float* __restrict__ out) {
    const float* __restrict__ tab = ws + WS_CS;
    int tid = threadIdx.x;
    int p = blockIdx.x * 256 + tid;
    int b = p / (HH * WW);
    int rem = p - b * (HH * WW);
    int y = rem / WW;
    int x = rem - y * WW;
    float xc = (float)x - (WW * 0.5f);
    float yc = (float)y - (HH * 0.5f);
    const float* f = ws + WS_FILT + b * (NA * ND);
    float acc = 0.f;
    float r2 = xc * xc + yc * yc;
    if (r2 < 256.0f) {
        for (int a = 0; a < NA; ++a) {
            float c = tab[2 * a], s = tab[2 * a + 1];
            float rot = xc * c + yc * s;
            float t = (rot * 0.15915494309189535f) * 729.0f;
            int i = (int)t;
            i = i < 0 ? 0 : (i > (ND - 1) ? (ND - 1) : i);
            acc += f[a * ND + i];
        }
    } else {
        float r = sqrtf(r2);
        float phi = atan2f(yc, xc);
        float cen = (phi < -1.5707964f) ? phi + 6.2831855f : phi;
        float theta = acosf(6.27457f / r);
        float tc = cen * 56.971835f;                 // *(179/pi)
        float w = theta * 56.971835f;
        int hs = (int)ceilf(tc - w) + 1;
        int he = (int)floorf(tc + w) - 1;
        int le = (int)floorf(tc - 89.5f) - 1;
        int rs = (int)ceilf(tc + 89.5f) + 1;
        hs = hs < 0 ? 0 : hs;
        he = he > (NA - 1) ? (NA - 1) : he;
        const float* P0 = ws + WS_P0 + b * 192;
        const float* P728 = ws + WS_P728 + b * 192;
        if (le >= 0) acc += P0[le + 1];
        if (rs <= NA - 1) acc += P0[NA] - P0[rs];
        if (he >= hs) acc += P728[he + 1] - P728[hs];
        int b1s = le + 1 < 0 ? 0 : le + 1;
        int b1e = hs - 1 > (NA - 1) ? (NA - 1) : hs - 1;
        int b2s = he + 1 < 0 ? 0 : he + 1;
        int b2e = rs - 1 > (NA - 1) ? (NA - 1) : rs - 1;
        for (int a = b1s; a <= b1e; ++a) {
            float c = tab[2 * a], s = tab[2 * a + 1];
            float rot = xc * c + yc * s;
            float t = (rot * 0.15915494309189535f) * 729.0f;
            int i = (int)t;
            i = i < 0 ? 0 : (i > (ND - 1) ? (ND - 1) : i);
            acc += f[a * ND + i];
        }
        for (int a = b2s; a <= b2e; ++a) {
            float c = tab[2 * a], s = tab[2 * a + 1];
            float rot = xc * c + yc * s;
            float t = (rot * 0.15915494309189535f) * 729.0f;
            int i = (int)t;
            i = i < 0 ? 0 : (i > (ND - 1) ? (ND - 1) : i);
            acc += f[a * ND + i];
        }
    }
    out[p] = fmaxf(acc * (float)(M_PI / NA), 0.0f);  // clip(.,0,max) == relu
}

extern "C" void kernel_launch(void* const* d_in, const int* in_sizes, int n_in,
                              void* d_out, int out_size, void* d_ws, size_t ws_size,
                              hipStream_t stream) {
    const float* sino = (const float*)d_in[0];
    float* out = (float*)d_out;
    float* ws = (float*)d_ws;

    hipMemsetAsync(ws, 0, 4, stream);   // zero the completion counter
    hipLaunchKernelGGL(k_fused, dim3(361), dim3(256), 0, stream, sino, ws);
    hipLaunchKernelGGL(k_bp, dim3((NB * HH * WW) / 256), dim3(256), 0, stream, ws, out);
}

// Round 8
// 82.059 us; speedup vs baseline: 1.4298x; 1.4298x over previous
//
#include <hip/hip_runtime.h>
#include <math.h>

#define HH 512
#define WW 512
#define NA 180
#define ND 729
#define NB 2

// ws layout (float units):
//   [1024, 1024+360)   interleaved {cos,sin} per angle
//   [4096, ...)        filtered sinograms
#define WS_CS 1024
#define WS_FILT 4096

// Ram-Lak spatial kernel (closed form, validated R2-R7):
//   g[d] = (0.125 + min(d,729-d)/1458)/729 — piecewise LINEAR in d, so the
// 729-tap circular convolution is O(1) per output via prefix moments
//   P[k] = sum_{j<k} x[j],  Q[k] = sum_{j<k} j*x[j]  (double precision):
//   filtered[n] = c0*X + c1*(A(n)+B(n)), c0 = 0.125/729, c1 = 1/(1458*729)
//   A(n) = sum_{d=1..364} d*x[(n-d)%729], B(n) = sum_{d=1..364} d*x[(n+d)%729]
// (expansions below; edge cases n in {0,364,728} hand-verified; absmax canary
// 7.629395e-06 bit-identical through the R7 switch to this math).
// NO fence / atomic / last-block-done: R5+R7 showed __threadfence() in every
// block costs ~40us (device-scope L2 writeback storm); separate nodes are
// ~8-10us. One block per row; block 360 writes the angle tables.
__global__ __launch_bounds__(256, 1) void k_filter(const float* __restrict__ sino,
                                                   float* __restrict__ ws) {
    int blk = blockIdx.x;
    int tid = threadIdx.x;
    if (blk == 360) {   // angle tables
        for (int t = tid; t < NA; t += 256) {
            double ang = M_PI * (double)t / (double)(NA - 1);
            ws[WS_CS + 2 * t] = (float)cos(ang);
            ws[WS_CS + 2 * t + 1] = (float)sin(ang);
        }
        return;
    }
    __shared__ float xs[736];
    __shared__ double Pd[730], Qd[730];
    __shared__ double sp[256], sq[256];
    const float* x = sino + blk * ND;
    for (int i = tid; i < 736; i += 256) xs[i] = (i < ND) ? x[i] : 0.0f;
    __syncthreads();
    double lx = 0.0, lq = 0.0;
    if (tid < 243) {
        #pragma unroll
        for (int k = 0; k < 3; ++k) {
            int j = 3 * tid + k;
            double v = (double)xs[j];
            lx += v;
            lq += (double)j * v;
        }
    }
    sp[tid] = lx;
    sq[tid] = lq;
    __syncthreads();
    for (int off = 1; off < 256; off <<= 1) {   // inclusive Hillis-Steele
        double ap = (tid >= off) ? sp[tid - off] : 0.0;
        double aq = (tid >= off) ? sq[tid - off] : 0.0;
        __syncthreads();
        sp[tid] += ap;
        sq[tid] += aq;
        __syncthreads();
    }
    if (tid < 243) {                            // exclusive P[0..729], Q[0..729]
        double bp_ = tid ? sp[tid - 1] : 0.0;
        double bq_ = tid ? sq[tid - 1] : 0.0;
        #pragma unroll
        for (int k = 0; k < 3; ++k) {
            int j = 3 * tid + k;
            Pd[j] = bp_;
            Qd[j] = bq_;
            double v = (double)xs[j];
            bp_ += v;
            bq_ += (double)j * v;
        }
    }
    if (tid == 0) { Pd[ND] = sp[242]; Qd[ND] = sq[242]; }
    __syncthreads();
    const double X = Pd[ND], M = Qd[ND];
    const double c0 = 0.125 / 729.0;
    const double c1 = 1.0 / (1458.0 * 729.0);
    float* f = ws + WS_FILT + blk * ND;
    for (int n = tid; n < ND; n += 256) {
        double dn = (double)n;
        double A, Bv;
        if (n >= 364) A = dn * (Pd[n] - Pd[n - 364]) - (Qd[n] - Qd[n - 364]);
        else          A = dn * Pd[n] - Qd[n]
                        + (dn + 729.0) * (X - Pd[n + 365]) - (M - Qd[n + 365]);
        if (n <= 364) Bv = (Qd[n + 365] - Qd[n + 1]) - dn * (Pd[n + 365] - Pd[n + 1]);
        else          Bv = (M - Qd[n + 1]) - dn * (X - Pd[n + 1])
                         + Qd[n - 364] + (729.0 - dn) * Pd[n - 364];
        f[n] = (float)(c0 * X + c1 * (A + Bv));
    }
}

// Backprojection. idx(a) = clip(trunc((rot*c1)*729), 0, 728), rot = xc*cos+yc*sin.
// For r>=16 the angle axis splits into [low | band | high | band | low]:
//   high (idx=728): rot >= 6.27457  <=>  |a-phi| <= theta, theta = acos(6.27457/r)
//   low  (idx=0):   rot <  0.008619 <=>  |a-phi| >  ~pi/2
// Edges via atan2f/acosf (+-1 index guard, ~250x margin); guarded band uses
// exact original arithmetic; clamped cores use P0/P728 prefix sums computed
// IN-BLOCK here (each block serves one batch): bit-identical f32 Hillis-Steele
// as the former k_prefix kernel — removes that node without any fence.
__global__ __launch_bounds__(256) void k_bp(const float* __restrict__ ws,
                                            float* __restrict__ out) {
    const float* __restrict__ tab = ws + WS_CS;
    __shared__ float s0[256], s1[256];
    __shared__ float P0s[NA + 1], P7s[NA + 1];
    int tid = threadIdx.x;
    int p = blockIdx.x * 256 + tid;
    int b = p / (HH * WW);
    const float* f = ws + WS_FILT + b * (NA * ND);
    float v0 = 0.f, v1 = 0.f;
    if (tid < NA) {
        v0 = f[tid * ND];
        v1 = f[tid * ND + (ND - 1)];
    }
    s0[tid] = v0;
    s1[tid] = v1;
    __syncthreads();
    for (int off = 1; off < 256; off <<= 1) {
        float a0 = (tid >= off) ? s0[tid - off] : 0.f;
        float a1 = (tid >= off) ? s1[tid - off] : 0.f;
        __syncthreads();
        s0[tid] += a0;
        s1[tid] += a1;
        __syncthreads();
    }
    if (tid == 0) { P0s[0] = 0.f; P7s[0] = 0.f; }
    if (tid < NA) { P0s[tid + 1] = s0[tid]; P7s[tid + 1] = s1[tid]; }
    __syncthreads();
    int rem = p - b * (HH * WW);
    int y = rem / WW;
    int x = rem - y * WW;
    float xc = (float)x - (WW * 0.5f);
    float yc = (float)y - (HH * 0.5f);
    float acc = 0.f;
    float r2 = xc * xc + yc * yc;
    if (r2 < 256.0f) {
        for (int a = 0; a < NA; ++a) {
            float c = tab[2 * a], s = tab[2 * a + 1];
            float rot = xc * c + yc * s;
            float t = (rot * 0.15915494309189535f) * 729.0f;
            int i = (int)t;
            i = i < 0 ? 0 : (i > (ND - 1) ? (ND - 1) : i);
            acc += f[a * ND + i];
        }
    } else {
        float r = sqrtf(r2);
        float phi = atan2f(yc, xc);
        float cen = (phi < -1.5707964f) ? phi + 6.2831855f : phi;
        float theta = acosf(6.27457f / r);
        float tc = cen * 56.971835f;                 // *(179/pi)
        float w = theta * 56.971835f;
        int hs = (int)ceilf(tc - w) + 1;
        int he = (int)floorf(tc + w) - 1;
        int le = (int)floorf(tc - 89.5f) - 1;
        int rs = (int)ceilf(tc + 89.5f) + 1;
        hs = hs < 0 ? 0 : hs;
        he = he > (NA - 1) ? (NA - 1) : he;
        if (le >= 0) acc += P0s[le + 1];
        if (rs <= NA - 1) acc += P0s[NA] - P0s[rs];
        if (he >= hs) acc += P7s[he + 1] - P7s[hs];
        int b1s = le + 1 < 0 ? 0 : le + 1;
        int b1e = hs - 1 > (NA - 1) ? (NA - 1) : hs - 1;
        int b2s = he + 1 < 0 ? 0 : he + 1;
        int b2e = rs - 1 > (NA - 1) ? (NA - 1) : rs - 1;
        for (int a = b1s; a <= b1e; ++a) {
            float c = tab[2 * a], s = tab[2 * a + 1];
            float rot = xc * c + yc * s;
            float t = (rot * 0.15915494309189535f) * 729.0f;
            int i = (int)t;
            i = i < 0 ? 0 : (i > (ND - 1) ? (ND - 1) : i);
            acc += f[a * ND + i];
        }
        for (int a = b2s; a <= b2e; ++a) {
            float c = tab[2 * a], s = tab[2 * a + 1];
            float rot = xc * c + yc * s;
            float t = (rot * 0.15915494309189535f) * 729.0f;
            int i = (int)t;
            i = i < 0 ? 0 : (i > (ND - 1) ? (ND - 1) : i);
            acc += f[a * ND + i];
        }
    }
    out[p] = fmaxf(acc * (float)(M_PI / NA), 0.0f);  // clip(.,0,max) == relu
}

extern "C" void kernel_launch(void* const* d_in, const int* in_sizes, int n_in,
                              void* d_out, int out_size, void* d_ws, size_t ws_size,
                              hipStream_t stream) {
    const float* sino = (const float*)d_in[0];
    float* out = (float*)d_out;
    float* ws = (float*)d_ws;

    hipLaunchKernelGGL(k_filter, dim3(361), dim3(256), 0, stream, sino, ws);
    hipLaunchKernelGGL(k_bp, dim3((NB * HH * WW) / 256), dim3(256), 0, stream, ws, out);
}